// Round 20
// baseline (810.670 us; speedup 1.0000x reference)
//
#include <hip/hip_runtime.h>
#include <hip/hip_bf16.h>

#define NROW 8192
#define NDIM 256
#define INV_T (1.0f / 0.07f)
#define K_BOT 819      // first selected descending rank
#define K_TOP 4095     // one past last selected rank
#define N_SEL 3276
#define N_UNSEL 4916   // 8192 - N_SEL (includes diagonal at -10)
#define KLO 0xC100u    // key of value 8.0
#define KHI 0xC280u    // key of value 64.0
#define RSPAN 0x180u   // 384 keys, 3 slots of 128

typedef unsigned int u32;
typedef unsigned short u16;
typedef short s16;
typedef unsigned long long u64;
typedef __bf16 bf16_t;
typedef s16 s16x8 __attribute__((ext_vector_type(8)));
typedef float f32x4 __attribute__((ext_vector_type(4)));

__device__ __forceinline__ u16 bfbits(float f) {
    return __builtin_bit_cast(u16, (bf16_t)f);   // RNE f32->bf16, raw bits
}
__device__ __forceinline__ u16 map16(u16 b) {
    return (b & 0x8000u) ? (u16)~b : (u16)(b | 0x8000u);
}
__device__ __forceinline__ float unmap16(u32 m) {
    u16 b = (m & 0x8000u) ? (u16)(m & 0x7FFFu) : (u16)~(u16)m;
    return __uint_as_float(((u32)b) << 16);
}
__device__ __forceinline__ float bf2f(s16 v) {
    return __uint_as_float(((u32)(u16)v) << 16);
}

__device__ __forceinline__ void gload16(const void* g, void* l) {
    __builtin_amdgcn_global_load_lds(
        (const __attribute__((address_space(1))) u32*)g,
        (__attribute__((address_space(3))) u32*)l, 16, 0, 0);
}

__device__ __forceinline__ u32 wave_sum_u32(u32 x) {
#pragma unroll
    for (int o = 32; o; o >>= 1) x += __shfl_down(x, o);
    return __shfl(x, 0);
}

// resolve rank `rem` within a 128-key sub-hist (packed u16 counts, 64 words)
__device__ __forceinline__ void resolve_slot(const u32* sub, int slot, u32 rem,
                                             int lane, u32* idxOut, u32* gtOut) {
    u32 word = sub[slot * 64 + lane];
    u32 c0 = word & 0xFFFFu, c1 = word >> 16;
    u32 s0 = c0 + c1, suf = s0;
#pragma unroll
    for (int o = 1; o < 64; o <<= 1) {
        u32 v = __shfl_down(suf, o);
        if (lane + o < 64) suf += v;
    }
    u32 TexL = suf - s0;
    u32 f = 0, pk = 0;
    u32 ab0 = TexL + c1;
    if (rem >= ab0 && rem < ab0 + c0) { f = 1; pk = ((u32)(lane * 2) << 16) | ab0; }
    if (rem >= TexL && rem < TexL + c1) { f = 1; pk = ((u32)(lane * 2 + 1) << 16) | TexL; }
    u64 mm = __ballot(f != 0);
    pk = __shfl(pk, (int)(__ffsll((unsigned long long)mm) - 1));
    *idxOut = pk >> 16;
    *gtOut = pk & 0xFFFFu;
}

// ---------------- zero the stats region (6.03 MB, exact cover) -----------
__global__ __launch_bounds__(256) void zero_stats(u32* __restrict__ p) {
    int i = (blockIdx.x * 256 + threadIdx.x) * 4;
    *(uint4*)(p + i) = make_uint4(0, 0, 0, 0);
}

// ---------------- fp32 -> bf16 (both inputs, one launch) ----------------
__global__ __launch_bounds__(256) void cvt_bf16(const float* __restrict__ in0,
                                                const float* __restrict__ in1,
                                                u16* __restrict__ out0,
                                                u16* __restrict__ out1) {
    int b = blockIdx.x;
    const float* in = (b < 2048) ? in0 : in1;
    u16* out = (b < 2048) ? out0 : out1;
    int i = ((b & 2047) * 256 + threadIdx.x) * 4;
    float4 v = *(const float4*)(in + i);
    ushort4 o;
    o.x = bfbits(v.x); o.y = bfbits(v.y); o.z = bfbits(v.z); o.w = bfbits(v.w);
    *(ushort4*)(out + i) = o;
}

// ---------------- GEMM -> per-row rank stats (keys never materialized) ----
// Proven round-14 GEMM core: 128x128 tile, BK=64, 8 waves, wave tile 64x32.
// Epilogue: per-key global atomic stats — statsSub[row][3][64] packed-u16
// counts for R=[8,64); statsHi[row] = count of keys >= 64 (values>=64 are
// ~nonexistent -> almost no atomics). Diagonal skipped.
__global__ __launch_bounds__(512) void gemm_stats(const u16* __restrict__ Qb,
                                                  const u16* __restrict__ Kb,
                                                  u32* __restrict__ statsSub,
                                                  u32* __restrict__ statsHi) {
    constexpr int BK = 64;
    __shared__ __align__(16) u16 sA[128 * BK];   // 16 KB
    __shared__ __align__(16) u16 sB[128 * BK];   // 16 KB

    const int tid  = threadIdx.x;
    const int lane = tid & 63;
    const int wid  = tid >> 6;
    const int wr = wid & 1;
    const int wc = wid >> 1;
    const int r0 = blockIdx.y * 128;
    const int bn = blockIdx.x * 128;
    const int kg = lane >> 4;
    const int fr = lane & 15;
    const int srr = lane >> 3;
    const int srj = (lane & 7) ^ srr;

    f32x4 acc[4][2] = {};

    for (int k0 = 0; k0 < NDIM; k0 += BK) {
        __syncthreads();
#pragma unroll
        for (int s = 0; s < 2; ++s) {
            int seg = wid * 2 + s;
            int row = seg * 8 + srr;
            gload16(Qb + (size_t)(r0 + row) * NDIM + k0 + srj * 8, &sA[seg * 512]);
            gload16(Kb + (size_t)(bn + row) * NDIM + k0 + srj * 8, &sB[seg * 512]);
        }
        __syncthreads();

#pragma unroll
        for (int kk = 0; kk < 2; ++kk) {
            s16x8 af[4], bfv[2];
            const int jp = (kk * 4 + kg) ^ (fr & 7);
#pragma unroll
            for (int m = 0; m < 4; ++m) {
                int row = wr * 64 + m * 16 + fr;
                af[m] = *(const s16x8*)(&sA[row * BK + jp * 8]);
            }
#pragma unroll
            for (int n = 0; n < 2; ++n) {
                int row = wc * 32 + n * 16 + fr;
                bfv[n] = *(const s16x8*)(&sB[row * BK + jp * 8]);
            }
#pragma unroll
            for (int m = 0; m < 4; ++m)
#pragma unroll
                for (int n = 0; n < 2; ++n)
                    acc[m][n] = __builtin_amdgcn_mfma_f32_16x16x32_bf16(
                        af[m], bfv[n], acc[m][n], 0, 0, 0);
        }
    }

    // epilogue: stats from registers (byte-packed cntHi per (m, jj))
    u32 cnt[4] = {0, 0, 0, 0};
#pragma unroll
    for (int m = 0; m < 4; ++m)
#pragma unroll
        for (int n = 0; n < 2; ++n)
#pragma unroll
            for (int jj = 0; jj < 4; ++jj) {
                int rowL = wr * 64 + m * 16 + kg * 4 + jj;
                int grow = r0 + rowL;
                int gcol = bn + wc * 32 + n * 16 + fr;
                u32 key = (u32)map16(bfbits(acc[m][n][jj]));
                if (grow != gcol) {
                    cnt[m] += ((key >= KHI) ? 1u : 0u) << (jj * 8);
                    u32 d = key - KLO;
                    if (d < RSPAN)
                        atomicAdd(&statsSub[(size_t)grow * 192 +
                                            (size_t)((d >> 7) * 64 + ((key >> 1) & 63u))],
                                  (key & 1u) ? 0x10000u : 1u);
                }
            }
#pragma unroll
    for (int m = 0; m < 4; ++m) {
        u32 v = cnt[m];
        v += __shfl_down(v, 8, 16);
        v += __shfl_down(v, 4, 16);
        v += __shfl_down(v, 2, 16);
        v += __shfl_down(v, 1, 16);
        if (fr == 0 && v) {
#pragma unroll
            for (int jj = 0; jj < 4; ++jj) {
                u32 b = (v >> (jj * 8)) & 255u;
                if (b) atomicAdd(&statsHi[r0 + wr * 64 + m * 16 + kg * 4 + jj], b);
            }
        }
    }
}

// ---------------- resolve: round-18 fast path on stats + inline fallback --
__global__ __launch_bounds__(128) void resolve(const u16* __restrict__ Qb,
                                               const u16* __restrict__ Kb,
                                               const float* __restrict__ fq,
                                               const float* __restrict__ fk,
                                               const u32* __restrict__ statsSub,
                                               const u32* __restrict__ statsHi,
                                               float* __restrict__ loss) {
    __shared__ u32 subs[2][192];
    __shared__ u16 skey[2][NROW];   // 32 KB, used only on the (rare) fallback
    const int t = threadIdx.x, w = t >> 6, lane = t & 63;
    const int row = blockIdx.x * 2 + w;

    // copy this row's stats to LDS (wave-private; DS in-order per wave)
    const u32* gsub = statsSub + (size_t)row * 192;
    u32 w0 = gsub[lane], w1 = gsub[64 + lane], w2 = gsub[128 + lane];
    u32* sub = subs[w];
    sub[lane] = w0; sub[64 + lane] = w1; sub[128 + lane] = w2;
    const u32 CH = statsHi[row];

    // exact fp32 l_pos
    float lp;
    {
        float4 q4 = *(const float4*)(fq + (size_t)row * NDIM + lane * 4);
        float4 k4 = *(const float4*)(fk + (size_t)row * NDIM + lane * 4);
        float p = q4.x * k4.x + q4.y * k4.y + q4.z * k4.z + q4.w * k4.w;
#pragma unroll
        for (int o = 32; o; o >>= 1) p += __shfl_down(p, o);
        lp = __shfl(p, 0);
    }

    // slot totals
    u32 T0, T1, T2;
    {
        u32 m0 = (w0 & 0xFFFFu) + (w0 >> 16);
        u32 m1 = (w1 & 0xFFFFu) + (w1 >> 16);
        u32 m2 = (w2 & 0xFFFFu) + (w2 >> 16);
        u32 p01 = wave_sum_u32(m0 | (m1 << 16));
        T2 = wave_sum_u32(m2);
        T0 = p01 & 0xFFFFu; T1 = p01 >> 16;
    }
    const u32 NR = T0 + T1 + T2;

    bool fb = !((CH <= (u32)K_BOT) && ((u32)K_BOT < CH + NR))
            || ((u32)(K_TOP - 1) < CH + NR);

    u32 ua = 0, Ga = 0, Ea = 0;
    float a = 0.f;
    if (!fb) {
        const u32 AT2 = CH, AT1 = CH + T2, AT0 = AT1 + T1;
        int sA_;
        u32 ATA;
        if ((u32)K_BOT >= AT0)      { sA_ = 0; ATA = AT0; }
        else if ((u32)K_BOT >= AT1) { sA_ = 1; ATA = AT1; }
        else                        { sA_ = 2; ATA = AT2; }
        const u32 remA = (u32)K_BOT - ATA;
        u32 idxA, gtA;
        resolve_slot(sub, sA_, remA, lane, &idxA, &gtA);
        ua = KLO + ((u32)sA_ << 7) + idxA;
        Ga = ATA + gtA;
        {
            u32 wv = sub[sA_ * 64 + (idxA >> 1)];
            Ea = (idxA & 1u) ? (wv >> 16) : (wv & 0xFFFFu);
        }
        a = unmap16(ua);
        if (!(a >= 10.9f)) fb = true;   // significance guard for dropped terms
    }

    if (!fb) {
        const float m_ = fmaxf(fmaxf(lp, a), -10.0f) * INV_T;
        float sm = 0.f;
#pragma unroll
        for (int s = 0; s < 3; ++s) {
            u32 wv = sub[s * 64 + lane];
            u32 c0 = wv & 0xFFFFu, c1 = wv >> 16;
            u32 k0 = KLO + ((u32)s << 7) + (u32)(lane * 2);
            u32 k1 = k0 | 1u;
            if (c0 && k0 < ua) sm += (float)c0 * __expf(unmap16(k0) * INV_T - m_);
            if (c1 && k1 < ua) sm += (float)c1 * __expf(unmap16(k1) * INV_T - m_);
        }
#pragma unroll
        for (int o = 32; o; o >>= 1) sm += __shfl_down(sm, o);
        if (lane == 0) {
            float expA = __expf(a * INV_T - m_);
            float tot = sm + (float)(int)(Ga + Ea - (u32)K_BOT) * expA;
            tot += __expf(lp * INV_T - m_)
                 + (float)N_UNSEL * __expf(-10.0f * INV_T - m_);
            loss[row] = m_ + __logf(tot) - lp * INV_T;
        }
    } else {
        // exact fallback: recompute the key row, bisect both ranks, tie-exact
        u16* K = skey[w];
        for (int j = 0; j < 128; ++j) {
            int c = j * 64 + lane;
            float dot = 0.f;
            for (int kc = 0; kc < 32; ++kc) {
                s16x8 qv = *(const s16x8*)(Qb + (size_t)row * NDIM + kc * 8);
                s16x8 kv = *(const s16x8*)(Kb + (size_t)c * NDIM + kc * 8);
#pragma unroll
                for (int e = 0; e < 8; ++e) dot += bf2f(qv[e]) * bf2f(kv[e]);
            }
            K[c] = (c == row) ? (u16)0 : map16(bfbits(dot));
        }
        auto cntAbove = [&](u32 mid) {
            u32 pc = 0;
            for (int i = 0; i < 128; ++i) pc += (u32)(K[i * 64 + lane] > mid);
            return wave_sum_u32(pc);
        };
        u32 lo = 0, hi = 65535;
        while (lo < hi) { u32 mid = (lo + hi) >> 1;
            if (cntAbove(mid) <= (u32)K_BOT) hi = mid; else lo = mid + 1; }
        const u32 fua = lo;
        lo = 0; hi = 65535;
        while (lo < hi) { u32 mid = (lo + hi) >> 1;
            if (cntAbove(mid) <= (u32)(K_TOP - 1)) hi = mid; else lo = mid + 1; }
        const u32 fub = lo;
        const float fa = unmap16(fua);
        const float m_ = fmaxf(fmaxf(lp, fa), -10.0f) * INV_T;
        u32 cga = 0, cea = 0, cgb = 0;
        float sm = 0.f;
        for (int i = 0; i < 128; ++i) {
            u32 u = K[i * 64 + lane];
            cga += (u > fua); cea += (u == fua); cgb += (u > fub);
            if (u > fub && u < fua) sm += __expf(unmap16(u) * INV_T - m_);
        }
        u32 fGa = wave_sum_u32(cga), fEa = wave_sum_u32(cea), fGb = wave_sum_u32(cgb);
#pragma unroll
        for (int o = 32; o; o >>= 1) sm += __shfl_down(sm, o);
        if (lane == 0) {
            float bv = unmap16(fub);
            float expA = __expf(fa * INV_T - m_);
            float tot;
            if (fua == fub) {
                tot = (float)N_SEL * expA;
            } else {
                float expB = __expf(bv * INV_T - m_);
                tot = sm + (float)(int)(fGa + fEa - (u32)K_BOT) * expA
                         + (float)(int)((u32)K_TOP - fGb) * expB;
            }
            tot += __expf(lp * INV_T - m_)
                 + (float)N_UNSEL * __expf(-10.0f * INV_T - m_);
            loss[row] = m_ + __logf(tot) - lp * INV_T;
        }
    }
}

// ---------------- host ----------------
extern "C" void kernel_launch(void* const* d_in, const int* in_sizes, int n_in,
                              void* d_out, int out_size, void* d_ws, size_t ws_size,
                              hipStream_t stream) {
    const float* fq = (const float*)d_in[0];
    const float* fk = (const float*)d_in[1];
    float* out = (float*)d_out;

    char* ws = (char*)d_ws;
    u16* qb = (u16*)ws;                                    // 4 MiB
    u16* kb = qb + (size_t)NROW * NDIM;                    // 4 MiB
    u32* statsSub = (u32*)(ws + 2 * (size_t)NROW * NDIM * 2);  // 6 MiB
    u32* statsHi = statsSub + (size_t)NROW * 192;          // 32 KiB (contiguous)

    zero_stats<<<1544, 256, 0, stream>>>(statsSub);        // covers sub+hi exactly
    cvt_bf16<<<4096, 256, 0, stream>>>(fq, fk, qb, kb);
    gemm_stats<<<dim3(64, 64), 512, 0, stream>>>(qb, kb, statsSub, statsHi);
    resolve<<<NROW / 2, 128, 0, stream>>>(qb, kb, fq, fk, statsSub, statsHi, out);
}